// Round 5
// baseline (2696.211 us; speedup 1.0000x reference)
//
#include <hip/hip_runtime.h>
#include <cstdint>
#include <cstddef>

#define B_ 2
#define S_ 2048
#define HID_ 1024
#define H_ 16
#define DH_ 64

typedef __attribute__((ext_vector_type(8))) short short8;
typedef __attribute__((ext_vector_type(8))) unsigned short ushort8;
typedef __attribute__((ext_vector_type(4))) float floatx4;
typedef __attribute__((ext_vector_type(4))) float float4v;

static __device__ __forceinline__ unsigned short f2bf(float f) {
  unsigned int u = __float_as_uint(f);
  u += 0x7fffu + ((u >> 16) & 1u);
  return (unsigned short)(u >> 16);
}
static __device__ __forceinline__ float bf2f(unsigned short h) {
  return __uint_as_float(((unsigned int)h) << 16);
}

// ---------------------------------------------------------------------------
// Kernel 0: conversions. x -> bf16; w1 -> bf16 transposed [N][K];
// w2 -> split hi/lo bf16 transposed [N][K].  (unchanged from round 4)
// ---------------------------------------------------------------------------
__global__ __launch_bounds__(256) void convert_kernel(
    const float* __restrict__ x, const float* __restrict__ w1,
    const float* __restrict__ w2, unsigned short* __restrict__ x_bf,
    unsigned short* __restrict__ w1t, unsigned short* __restrict__ w2t_hi,
    unsigned short* __restrict__ w2t_lo) {
  const int NX = B_ * S_ * HID_;
  const int NW = HID_ * HID_;
  int idx = blockIdx.x * 256 + threadIdx.x;
  if (idx < NX) {
    x_bf[idx] = f2bf(x[idx]);
  } else if (idx < NX + NW) {
    int i = idx - NX;
    int n = i >> 10, k = i & 1023;
    w1t[i] = f2bf(w1[k * HID_ + n]);
  } else if (idx < NX + 2 * NW) {
    int i = idx - NX - NW;
    int n = i >> 10, k = i & 1023;
    float v = w2[k * HID_ + n];
    unsigned short h = f2bf(v);
    w2t_hi[i] = h;
    w2t_lo[i] = f2bf(v - bf2f(h));
  }
}

// ---------------------------------------------------------------------------
// Kernel A: per-head QKV projection + bias + rotary for ONE batch b.
// DIAGNOSTIC VARIANT: plain fp32 outputs (no bf16 splitting).
//   q_f[h,s,0:64]=q*cos, [64:128]=q*sin ; k_f likewise ; v_f[h,s,d].
// grid (S/64, H), block 256.
// ---------------------------------------------------------------------------
__global__ __launch_bounds__(256) void qkv_kernel(
    const float* __restrict__ x, const float* __restrict__ wq,
    const float* __restrict__ bq, const float* __restrict__ wk,
    const float* __restrict__ bk, const float* __restrict__ wv,
    const float* __restrict__ theta, float* __restrict__ q_f,
    float* __restrict__ k_f, float* __restrict__ v_f, int b) {
  __shared__ __align__(16) float xs[64 * 68];
  __shared__ __align__(16) float wqs[64 * 68];
  __shared__ __align__(16) float wks[64 * 68];
  __shared__ __align__(16) float wvs[64 * 68];

  int tid = threadIdx.x;
  int st = blockIdx.x, h = blockIdx.y;
  int s0 = st * 64;

#pragma unroll
  for (int i = 0; i < 4; ++i) {
    int cid = tid + i * 256;
    int r = cid >> 4, c4 = (cid & 15) * 4;
    *reinterpret_cast<float4v*>(&xs[r * 68 + c4]) =
        *reinterpret_cast<const float4v*>(x + ((size_t)(b * S_ + s0 + r)) * HID_ + h * DH_ + c4);
  }
#pragma unroll
  for (int i = 0; i < 4; ++i) {
    int cid = tid + i * 256;
    int d = cid >> 4, c4 = (cid & 15) * 4;
    *reinterpret_cast<float4v*>(&wqs[d * 68 + c4]) =
        *reinterpret_cast<const float4v*>(wq + (size_t)(h * DH_ + d) * DH_ + c4);
    *reinterpret_cast<float4v*>(&wks[d * 68 + c4]) =
        *reinterpret_cast<const float4v*>(wk + (size_t)(h * DH_ + d) * DH_ + c4);
    *reinterpret_cast<float4v*>(&wvs[d * 68 + c4]) =
        *reinterpret_cast<const float4v*>(wv + (size_t)(h * DH_ + d) * DH_ + c4);
  }
  __syncthreads();

  int rg = tid >> 3;
  int cg = tid & 7;
  int r0 = rg * 2, c0 = cg * 8;

  float aq[2][8], ak[2][8], av[2][8];
#pragma unroll
  for (int i = 0; i < 2; ++i)
#pragma unroll
    for (int j = 0; j < 8; ++j) { aq[i][j] = 0.f; ak[i][j] = 0.f; av[i][j] = 0.f; }

  for (int d = 0; d < 64; ++d) {
    float x0 = xs[(r0 + 0) * 68 + d];
    float x1 = xs[(r0 + 1) * 68 + d];
#pragma unroll
    for (int j = 0; j < 8; ++j) {
      float wqv = wqs[d * 68 + c0 + j];
      float wkv = wks[d * 68 + c0 + j];
      float wvv = wvs[d * 68 + c0 + j];
      aq[0][j] += x0 * wqv; aq[1][j] += x1 * wqv;
      ak[0][j] += x0 * wkv; ak[1][j] += x1 * wkv;
      av[0][j] += x0 * wvv; av[1][j] += x1 * wvv;
    }
  }

  float thv[8], bqv[8], bkv[8];
#pragma unroll
  for (int j = 0; j < 8; ++j) {
    thv[j] = theta[h * DH_ + c0 + j];
    bqv[j] = bq[h * DH_ + c0 + j];
    bkv[j] = bk[h * DH_ + c0 + j];
  }

#pragma unroll
  for (int i = 0; i < 2; ++i) {
    int s = s0 + r0 + i;
    size_t qbase = ((size_t)h * S_ + s) * 128;
    size_t vbase = ((size_t)h * S_ + s) * 64;
#pragma unroll
    for (int j = 0; j < 8; ++j) {
      float q = aq[i][j] + bqv[j];
      float k = ak[i][j] + bkv[j];
      float ang = (float)s * thv[j];
      float cs = cosf(ang), sn = sinf(ang);
      q_f[qbase + c0 + j] = q * cs;
      q_f[qbase + 64 + c0 + j] = q * sn;
      k_f[qbase + c0 + j] = k * cs;
      k_f[qbase + 64 + c0 + j] = k * sn;
      v_f[vbase + c0 + j] = av[i][j];
    }
  }
}

// ---------------------------------------------------------------------------
// Kernel B (DIAGNOSTIC): retention core in pure fp32 VALU, ONE batch b.
// grid (S/64, H), block 256. Thread (r = tid>>2, sub = tid&3):
//   phase 1: computes scores row r, key cols sub*16..+15 (explicit 128-dot)
//   phase 2: accumulates O[r][sub*16..+15] over the key tile
// Fused GroupNorm epilogue via small LDS reduction. No MFMA anywhere.
// ---------------------------------------------------------------------------
__global__ __launch_bounds__(256) void retention_valu_kernel(
    const float* __restrict__ q_f, const float* __restrict__ k_f,
    const float* __restrict__ v_f, const float* __restrict__ gn_w,
    const float* __restrict__ gn_b, float* __restrict__ retn, int b) {
  __shared__ __align__(16) float Ql[64 * 132];
  __shared__ __align__(16) float Kl[64 * 132];
  __shared__ __align__(16) float Vl[64 * 68];
  __shared__ __align__(16) float Sc[64 * 65];
  __shared__ float gnred[64][8];

  int tid = threadIdx.x;
  int qt = blockIdx.x, h = blockIdx.y;
  int s0 = qt * 64;

  const float lo_c = -6.2383246250395075f, hi_c = -3.4657359027997265f;
  float gam = 1.f - __expf(lo_c + (hi_c - lo_c) * ((float)h * (1.f / 15.f)));
  float logg = __logf(gam);

  // stage Q tile: 64 rows x 128 (fp32)
#pragma unroll
  for (int i = 0; i < 8; ++i) {
    int cid = tid + i * 256;
    int r = cid >> 5, c4 = (cid & 31) * 4;
    *reinterpret_cast<float4v*>(&Ql[r * 132 + c4]) =
        *reinterpret_cast<const float4v*>(q_f + ((size_t)h * S_ + s0 + r) * 128 + c4);
  }

  int r = tid >> 2;   // 0..63: q-row within tile
  int sub = tid & 3;  // 0..3

  float acc[16];
#pragma unroll
  for (int i = 0; i < 16; ++i) acc[i] = 0.f;

  for (int kt = 0; kt <= qt; ++kt) {
    int t0 = kt * 64;
    __syncthreads();  // prev phase-2 reads of Kl/Vl/Sc done (also covers Ql stage)
#pragma unroll
    for (int i = 0; i < 8; ++i) {
      int cid = tid + i * 256;
      int rr = cid >> 5, c4 = (cid & 31) * 4;
      *reinterpret_cast<float4v*>(&Kl[rr * 132 + c4]) =
          *reinterpret_cast<const float4v*>(k_f + ((size_t)h * S_ + t0 + rr) * 128 + c4);
    }
#pragma unroll
    for (int i = 0; i < 4; ++i) {
      int cid = tid + i * 256;
      int rr = cid >> 4, c4 = (cid & 15) * 4;
      *reinterpret_cast<float4v*>(&Vl[rr * 68 + c4]) =
          *reinterpret_cast<const float4v*>(v_f + ((size_t)h * S_ + t0 + rr) * 64 + c4);
    }
    __syncthreads();

    // phase 1: scores for (row r, keys sub*16..+15)
    float sc[16];
#pragma unroll
    for (int i = 0; i < 16; ++i) sc[i] = 0.f;
    for (int k = 0; k < 128; ++k) {
      float qk = Ql[r * 132 + k];
#pragma unroll
      for (int i = 0; i < 16; ++i)
        sc[i] += qk * Kl[(sub * 16 + i) * 132 + k];
    }
#pragma unroll
    for (int i = 0; i < 16; ++i) {
      int tt = sub * 16 + i;
      int diff = (s0 + r) - (t0 + tt);
      Sc[r * 65 + tt] = (diff >= 0) ? sc[i] * __expf((float)diff * logg) : 0.f;
    }
    __syncthreads();

    // phase 2: O[r][sub*16+i] += sum_tt Sc[r][tt] * V[tt][sub*16+i]
    for (int tt = 0; tt < 64; ++tt) {
      float p = Sc[r * 65 + tt];
#pragma unroll
      for (int i = 0; i < 16; ++i)
        acc[i] += p * Vl[tt * 68 + sub * 16 + i];
    }
  }

  // GroupNorm over the 64 channels of row r (4 threads x 16 channels).
  float psum = 0.f, psq = 0.f;
#pragma unroll
  for (int i = 0; i < 16; ++i) { psum += acc[i]; psq += acc[i] * acc[i]; }
  __syncthreads();
  gnred[r][sub] = psum;
  gnred[r][4 + sub] = psq;
  __syncthreads();
  float sum = gnred[r][0] + gnred[r][1] + gnred[r][2] + gnred[r][3];
  float sq = gnred[r][4] + gnred[r][5] + gnred[r][6] + gnred[r][7];
  float mean = sum * (1.f / 64.f);
  float var = sq * (1.f / 64.f) - mean * mean;
  float rstd = rsqrtf(var + 1e-5f);

  size_t obase = ((size_t)(b * S_ + s0 + r)) * HID_ + h * DH_ + sub * 16;
#pragma unroll
  for (int i = 0; i < 16; ++i) {
    float gw = gn_w[h * DH_ + sub * 16 + i];
    float gb = gn_b[h * DH_ + sub * 16 + i];
    retn[obase + i] = (acc[i] - mean) * rstd * gw + gb;
  }
}

// ---------------------------------------------------------------------------
// GEMM 1 (gate): C = x_bf @ w1t^T (plain bf16), epilogue swish + retn,
// split result to pre_hi/pre_lo.  (unchanged from round 4)
// ---------------------------------------------------------------------------
__global__ __launch_bounds__(256) void gemm_gate_kernel(
    const unsigned short* __restrict__ A, const unsigned short* __restrict__ Bt,
    const float* __restrict__ retn, unsigned short* __restrict__ pre_hi,
    unsigned short* __restrict__ pre_lo) {
  const int K = HID_;
  __shared__ __align__(16) unsigned short Al[128 * 56];
  __shared__ __align__(16) unsigned short Bl[128 * 56];

  int tid = threadIdx.x;
  int lane = tid & 63, ln = lane & 15, quad = lane >> 4;
  int w = tid >> 6, wm = w >> 1, wn = w & 1;
  int m0 = blockIdx.y * 128, n0 = blockIdx.x * 128;

  floatx4 acc[4][4];
#pragma unroll
  for (int i = 0; i < 4; ++i)
#pragma unroll
    for (int j = 0; j < 4; ++j) acc[i][j] = (floatx4){0.f, 0.f, 0.f, 0.f};

  for (int k0 = 0; k0 < K; k0 += 32) {
    __syncthreads();
#pragma unroll
    for (int i = 0; i < 2; ++i) {
      int cid = tid + i * 256;
      int r = cid >> 2, c8 = (cid & 3) * 8;
      *reinterpret_cast<ushort8*>(&Al[r * 56 + c8]) =
          *reinterpret_cast<const ushort8*>(A + (size_t)(m0 + r) * K + k0 + c8);
      *reinterpret_cast<ushort8*>(&Bl[r * 56 + c8]) =
          *reinterpret_cast<const ushort8*>(Bt + (size_t)(n0 + r) * K + k0 + c8);
    }
    __syncthreads();

    short8 af[4], bfr[4];
#pragma unroll
    for (int i = 0; i < 4; ++i) {
      af[i] = *reinterpret_cast<const short8*>(&Al[(wm * 64 + i * 16 + ln) * 56 + quad * 8]);
      bfr[i] = *reinterpret_cast<const short8*>(&Bl[(wn * 64 + i * 16 + ln) * 56 + quad * 8]);
    }
#pragma unroll
    for (int mi = 0; mi < 4; ++mi)
#pragma unroll
      for (int ni = 0; ni < 4; ++ni)
        acc[mi][ni] = __builtin_amdgcn_mfma_f32_16x16x32_bf16(af[mi], bfr[ni], acc[mi][ni], 0, 0, 0);
  }

#pragma unroll
  for (int mi = 0; mi < 4; ++mi) {
#pragma unroll
    for (int r = 0; r < 4; ++r) {
      int row = m0 + wm * 64 + mi * 16 + quad * 4 + r;
#pragma unroll
      for (int ni = 0; ni < 4; ++ni) {
        int col = n0 + wn * 64 + ni * 16 + ln;
        float g = acc[mi][ni][r];
        float val = g * (1.f / (1.f + __expf(-g))) + retn[(size_t)row * HID_ + col];
        unsigned short hh = f2bf(val);
        size_t oidx = (size_t)row * HID_ + col;
        pre_hi[oidx] = hh;
        pre_lo[oidx] = f2bf(val - bf2f(hh));
      }
    }
  }
}

// ---------------------------------------------------------------------------
// GEMM 2 (output): C = pre @ w2t^T with split-bf16 A and B (3 MFMA products).
// Writes fp32 d_out.  (unchanged from round 4)
// ---------------------------------------------------------------------------
__global__ __launch_bounds__(256) void gemm_out_kernel(
    const unsigned short* __restrict__ Ah, const unsigned short* __restrict__ Alo,
    const unsigned short* __restrict__ Bth, const unsigned short* __restrict__ Btlo,
    float* __restrict__ out_f) {
  const int K = HID_;
  __shared__ __align__(16) unsigned short AhS[128 * 56];
  __shared__ __align__(16) unsigned short AlS[128 * 56];
  __shared__ __align__(16) unsigned short BhS[128 * 56];
  __shared__ __align__(16) unsigned short BlS[128 * 56];

  int tid = threadIdx.x;
  int lane = tid & 63, ln = lane & 15, quad = lane >> 4;
  int w = tid >> 6, wm = w >> 1, wn = w & 1;
  int m0 = blockIdx.y * 128, n0 = blockIdx.x * 128;

  floatx4 acc[4][4];
#pragma unroll
  for (int i = 0; i < 4; ++i)
#pragma unroll
    for (int j = 0; j < 4; ++j) acc[i][j] = (floatx4){0.f, 0.f, 0.f, 0.f};

  for (int k0 = 0; k0 < K; k0 += 32) {
    __syncthreads();
#pragma unroll
    for (int i = 0; i < 2; ++i) {
      int cid = tid + i * 256;
      int r = cid >> 2, c8 = (cid & 3) * 8;
      size_t ga = (size_t)(m0 + r) * K + k0 + c8;
      size_t gb = (size_t)(n0 + r) * K + k0 + c8;
      *reinterpret_cast<ushort8*>(&AhS[r * 56 + c8]) = *reinterpret_cast<const ushort8*>(Ah + ga);
      *reinterpret_cast<ushort8*>(&AlS[r * 56 + c8]) = *reinterpret_cast<const ushort8*>(Alo + ga);
      *reinterpret_cast<ushort8*>(&BhS[r * 56 + c8]) = *reinterpret_cast<const ushort8*>(Bth + gb);
      *reinterpret_cast<ushort8*>(&BlS[r * 56 + c8]) = *reinterpret_cast<const ushort8*>(Btlo + gb);
    }
    __syncthreads();

    short8 afh[4], afl[4], bfh[4], bfl[4];
#pragma unroll
    for (int i = 0; i < 4; ++i) {
      int ao = (wm * 64 + i * 16 + ln) * 56 + quad * 8;
      int bo = (wn * 64 + i * 16 + ln) * 56 + quad * 8;
      afh[i] = *reinterpret_cast<const short8*>(&AhS[ao]);
      afl[i] = *reinterpret_cast<const short8*>(&AlS[ao]);
      bfh[i] = *reinterpret_cast<const short8*>(&BhS[bo]);
      bfl[i] = *reinterpret_cast<const short8*>(&BlS[bo]);
    }
#pragma unroll
    for (int mi = 0; mi < 4; ++mi)
#pragma unroll
      for (int ni = 0; ni < 4; ++ni) {
        floatx4 a = acc[mi][ni];
        a = __builtin_amdgcn_mfma_f32_16x16x32_bf16(afh[mi], bfh[ni], a, 0, 0, 0);
        a = __builtin_amdgcn_mfma_f32_16x16x32_bf16(afl[mi], bfh[ni], a, 0, 0, 0);
        a = __builtin_amdgcn_mfma_f32_16x16x32_bf16(afh[mi], bfl[ni], a, 0, 0, 0);
        acc[mi][ni] = a;
      }
  }

#pragma unroll
  for (int mi = 0; mi < 4; ++mi) {
#pragma unroll
    for (int r = 0; r < 4; ++r) {
      int row = m0 + wm * 64 + mi * 16 + quad * 4 + r;
#pragma unroll
      for (int ni = 0; ni < 4; ++ni) {
        int col = n0 + wn * 64 + ni * 16 + ln;
        out_f[(size_t)row * HID_ + col] = acc[mi][ni][r];
      }
    }
  }
}

// ---------------------------------------------------------------------------
extern "C" void kernel_launch(void* const* d_in, const int* in_sizes, int n_in,
                              void* d_out, int out_size, void* d_ws,
                              size_t ws_size, hipStream_t stream) {
  (void)in_sizes; (void)n_in; (void)out_size; (void)ws_size;
  const float* x = (const float*)d_in[0];
  const float* wq = (const float*)d_in[1];
  const float* bq = (const float*)d_in[2];
  const float* wk = (const float*)d_in[3];
  const float* bk = (const float*)d_in[4];
  const float* wv = (const float*)d_in[5];
  const float* theta = (const float*)d_in[6];
  const float* gn_w = (const float*)d_in[7];
  const float* gn_b = (const float*)d_in[8];
  const float* w1 = (const float*)d_in[9];
  const float* w2 = (const float*)d_in[10];

  // Workspace: 70 MiB total (round 1 proved >= 76 MiB available).
  const size_t MB = 1024 * 1024;
  char* ws = (char*)d_ws;
  unsigned short* x_bf   = (unsigned short*)(ws + 0 * MB);    //  8 MiB
  unsigned short* w1t    = (unsigned short*)(ws + 8 * MB);    //  2 MiB
  unsigned short* w2t_hi = (unsigned short*)(ws + 10 * MB);   //  2 MiB
  unsigned short* w2t_lo = (unsigned short*)(ws + 12 * MB);   //  2 MiB
  float*          q_f    = (float*)(ws + 14 * MB);            // 16 MiB (1 batch)
  float*          k_f    = (float*)(ws + 30 * MB);            // 16 MiB
  float*          v_f    = (float*)(ws + 46 * MB);            //  8 MiB
  float*          retn   = (float*)(ws + 54 * MB);            // 16 MiB (both batches)
  // pre_hi/pre_lo alias q_f (dead after the second retention pass)
  unsigned short* pre_hi = (unsigned short*)(ws + 14 * MB);   //  8 MiB
  unsigned short* pre_lo = (unsigned short*)(ws + 22 * MB);   //  8 MiB
  float* out = (float*)d_out;

  convert_kernel<<<dim3(24576), 256, 0, stream>>>(x, w1, w2, x_bf, w1t, w2t_hi, w2t_lo);
  for (int b = 0; b < B_; ++b) {
    qkv_kernel<<<dim3(S_ / 64, H_), 256, 0, stream>>>(
        x, wq, bq, wk, bk, wv, theta, q_f, k_f, v_f, b);
    retention_valu_kernel<<<dim3(S_ / 64, H_), 256, 0, stream>>>(
        q_f, k_f, v_f, gn_w, gn_b, retn, b);
  }
  gemm_gate_kernel<<<dim3(HID_ / 128, (B_ * S_) / 128), 256, 0, stream>>>(
      x_bf, w1t, retn, pre_hi, pre_lo);
  gemm_out_kernel<<<dim3(HID_ / 128, (B_ * S_) / 128), 256, 0, stream>>>(
      pre_hi, pre_lo, w2t_hi, w2t_lo, out);
}

// Round 7
// 735.415 us; speedup vs baseline: 3.6662x; 3.6662x over previous
//
#include <hip/hip_runtime.h>
#include <cstdint>
#include <cstddef>

#define B_ 2
#define S_ 2048
#define HID_ 1024
#define H_ 16
#define DH_ 64

typedef __attribute__((ext_vector_type(8))) short short8;
typedef __attribute__((ext_vector_type(8))) unsigned short ushort8;
typedef __attribute__((ext_vector_type(4))) unsigned short ushort4v;
typedef __attribute__((ext_vector_type(4))) float floatx4;
typedef __attribute__((ext_vector_type(4))) float float4v;

static __device__ __forceinline__ unsigned short f2bf(float f) {
  unsigned int u = __float_as_uint(f);
  u += 0x7fffu + ((u >> 16) & 1u);
  return (unsigned short)(u >> 16);
}
static __device__ __forceinline__ float bf2f(unsigned short h) {
  return __uint_as_float(((unsigned int)h) << 16);
}

// ---------------------------------------------------------------------------
// Kernel 0: conversions. (unchanged, proven round 5)
// ---------------------------------------------------------------------------
__global__ __launch_bounds__(256) void convert_kernel(
    const float* __restrict__ x, const float* __restrict__ w1,
    const float* __restrict__ w2, unsigned short* __restrict__ x_bf,
    unsigned short* __restrict__ w1t, unsigned short* __restrict__ w2t_hi,
    unsigned short* __restrict__ w2t_lo) {
  const int NX = B_ * S_ * HID_;
  const int NW = HID_ * HID_;
  int idx = blockIdx.x * 256 + threadIdx.x;
  if (idx < NX) {
    x_bf[idx] = f2bf(x[idx]);
  } else if (idx < NX + NW) {
    int i = idx - NX;
    int n = i >> 10, k = i & 1023;
    w1t[i] = f2bf(w1[k * HID_ + n]);
  } else if (idx < NX + 2 * NW) {
    int i = idx - NX - NW;
    int n = i >> 10, k = i & 1023;
    float v = w2[k * HID_ + n];
    unsigned short h = f2bf(v);
    w2t_hi[i] = h;
    w2t_lo[i] = f2bf(v - bf2f(h));
  }
}

// ---------------------------------------------------------------------------
// Kernel A: per-head QKV projection + bias + rotary, fp32 out. (proven r5)
// ---------------------------------------------------------------------------
__global__ __launch_bounds__(256) void qkv_kernel(
    const float* __restrict__ x, const float* __restrict__ wq,
    const float* __restrict__ bq, const float* __restrict__ wk,
    const float* __restrict__ bk, const float* __restrict__ wv,
    const float* __restrict__ theta, float* __restrict__ q_f,
    float* __restrict__ k_f, float* __restrict__ v_f, int b) {
  __shared__ __align__(16) float xs[64 * 68];
  __shared__ __align__(16) float wqs[64 * 68];
  __shared__ __align__(16) float wks[64 * 68];
  __shared__ __align__(16) float wvs[64 * 68];

  int tid = threadIdx.x;
  int st = blockIdx.x, h = blockIdx.y;
  int s0 = st * 64;

#pragma unroll
  for (int i = 0; i < 4; ++i) {
    int cid = tid + i * 256;
    int r = cid >> 4, c4 = (cid & 15) * 4;
    *reinterpret_cast<float4v*>(&xs[r * 68 + c4]) =
        *reinterpret_cast<const float4v*>(x + ((size_t)(b * S_ + s0 + r)) * HID_ + h * DH_ + c4);
  }
#pragma unroll
  for (int i = 0; i < 4; ++i) {
    int cid = tid + i * 256;
    int d = cid >> 4, c4 = (cid & 15) * 4;
    *reinterpret_cast<float4v*>(&wqs[d * 68 + c4]) =
        *reinterpret_cast<const float4v*>(wq + (size_t)(h * DH_ + d) * DH_ + c4);
    *reinterpret_cast<float4v*>(&wks[d * 68 + c4]) =
        *reinterpret_cast<const float4v*>(wk + (size_t)(h * DH_ + d) * DH_ + c4);
    *reinterpret_cast<float4v*>(&wvs[d * 68 + c4]) =
        *reinterpret_cast<const float4v*>(wv + (size_t)(h * DH_ + d) * DH_ + c4);
  }
  __syncthreads();

  int rg = tid >> 3;
  int cg = tid & 7;
  int r0 = rg * 2, c0 = cg * 8;

  float aq[2][8], ak[2][8], av[2][8];
#pragma unroll
  for (int i = 0; i < 2; ++i)
#pragma unroll
    for (int j = 0; j < 8; ++j) { aq[i][j] = 0.f; ak[i][j] = 0.f; av[i][j] = 0.f; }

  for (int d = 0; d < 64; ++d) {
    float x0 = xs[(r0 + 0) * 68 + d];
    float x1 = xs[(r0 + 1) * 68 + d];
#pragma unroll
    for (int j = 0; j < 8; ++j) {
      float wqv = wqs[d * 68 + c0 + j];
      float wkv = wks[d * 68 + c0 + j];
      float wvv = wvs[d * 68 + c0 + j];
      aq[0][j] += x0 * wqv; aq[1][j] += x1 * wqv;
      ak[0][j] += x0 * wkv; ak[1][j] += x1 * wkv;
      av[0][j] += x0 * wvv; av[1][j] += x1 * wvv;
    }
  }

  float thv[8], bqv[8], bkv[8];
#pragma unroll
  for (int j = 0; j < 8; ++j) {
    thv[j] = theta[h * DH_ + c0 + j];
    bqv[j] = bq[h * DH_ + c0 + j];
    bkv[j] = bk[h * DH_ + c0 + j];
  }

#pragma unroll
  for (int i = 0; i < 2; ++i) {
    int s = s0 + r0 + i;
    size_t qbase = ((size_t)h * S_ + s) * 128;
    size_t vbase = ((size_t)h * S_ + s) * 64;
#pragma unroll
    for (int j = 0; j < 8; ++j) {
      float q = aq[i][j] + bqv[j];
      float k = ak[i][j] + bkv[j];
      float ang = (float)s * thv[j];
      float cs = cosf(ang), sn = sinf(ang);
      q_f[qbase + c0 + j] = q * cs;
      q_f[qbase + 64 + c0 + j] = q * sn;
      k_f[qbase + c0 + j] = k * cs;
      k_f[qbase + 64 + c0 + j] = k * sn;
      v_f[vbase + c0 + j] = av[i][j];
    }
  }
}

// ---------------------------------------------------------------------------
// Kernel B (BISECTION HYBRID): MFMA QK^T + decay -> fp32 Sc (round-5 layout),
// then round-5's PROVEN VALU PV phase + LDS GroupNorm epilogue, verbatim.
// No LDS aliasing. grid (S/64, H), block 256.
// If this passes, the round-6 bug is in {P bf16 relayout, PV-MFMA, shuffle
// epilogue}; if it fails, in {Q-frag load, K split staging, QK-MFMA, decay}.
// ---------------------------------------------------------------------------
__global__ __launch_bounds__(256) void retention_hybrid_kernel(
    const float* __restrict__ q_f, const float* __restrict__ k_f,
    const float* __restrict__ v_f, const float* __restrict__ gn_w,
    const float* __restrict__ gn_b, float* __restrict__ retn, int b) {
  __shared__ __align__(16) unsigned short Kh[64 * 136];   // 17 KiB
  __shared__ __align__(16) unsigned short Klo[64 * 136];  // 17 KiB
  __shared__ __align__(16) float Vl[64 * 68];             // 17 KiB (fp32, r5)
  __shared__ __align__(16) float Sc[64 * 65];             // 16.6 KiB (fp32, r5)
  __shared__ float gnred[64][8];

  int tid = threadIdx.x;
  int w = tid >> 6;
  int lane = tid & 63, ln = lane & 15, quad = lane >> 4;
  int qt = blockIdx.x, h = blockIdx.y;
  int s0 = qt * 64;

  const float lo_c = -6.2383246250395075f, hi_c = -3.4657359027997265f;
  float gam = 1.f - __expf(lo_c + (hi_c - lo_c) * ((float)h * (1.f / 15.f)));
  float logg = __logf(gam);

  // Q fragments (A-layout: m=ln, k=quad*8+j + 32c), split hi/lo in regs.
  int sQ = s0 + w * 16 + ln;
  const float* qrow = q_f + ((size_t)h * S_ + sQ) * 128 + quad * 8;
  short8 qh[4], ql[4];
#pragma unroll
  for (int c = 0; c < 4; ++c) {
#pragma unroll
    for (int j = 0; j < 8; ++j) {
      float qv = qrow[c * 32 + j];
      unsigned short hh = f2bf(qv);
      qh[c][j] = (short)hh;
      ql[c][j] = (short)f2bf(qv - bf2f(hh));
    }
  }

  // Phase-2 thread mapping (round 5, proven): row r2, channel group sub.
  int r2 = tid >> 2;
  int sub = tid & 3;
  float acc[16];
#pragma unroll
  for (int i = 0; i < 16; ++i) acc[i] = 0.f;

  for (int kt = 0; kt <= qt; ++kt) {
    int t0 = kt * 64;
    __syncthreads();  // prev phase-2 reads of Kh/Klo/Vl/Sc done

    // stage K tile 64x128: fp32 -> split bf16 (round-6 pattern, under test)
#pragma unroll
    for (int i = 0; i < 8; ++i) {
      int cid = tid + i * 256;
      int rr = cid >> 5, c4 = (cid & 31) * 4;
      float4v kv = *reinterpret_cast<const float4v*>(
          k_f + ((size_t)h * S_ + t0 + rr) * 128 + c4);
      ushort4v khv, klv;
#pragma unroll
      for (int k = 0; k < 4; ++k) {
        unsigned short hh = f2bf(kv[k]);
        khv[k] = hh;
        klv[k] = f2bf(kv[k] - bf2f(hh));
      }
      *reinterpret_cast<ushort4v*>(&Kh[rr * 136 + c4]) = khv;
      *reinterpret_cast<ushort4v*>(&Klo[rr * 136 + c4]) = klv;
    }
    // stage V tile fp32 (round-5 pattern, proven)
#pragma unroll
    for (int i = 0; i < 4; ++i) {
      int cid = tid + i * 256;
      int rr = cid >> 4, c4 = (cid & 15) * 4;
      *reinterpret_cast<float4v*>(&Vl[rr * 68 + c4]) =
          *reinterpret_cast<const float4v*>(v_f + ((size_t)h * S_ + t0 + rr) * 64 + c4);
    }
    __syncthreads();

    // QK^T split-MFMA (round-6 pattern, under test)
    floatx4 accS[4];
#pragma unroll
    for (int ns = 0; ns < 4; ++ns) {
      floatx4 a = (floatx4){0.f, 0.f, 0.f, 0.f};
#pragma unroll
      for (int ks = 0; ks < 4; ++ks) {
        int off = (ns * 16 + ln) * 136 + ks * 32 + quad * 8;
        short8 kh = *reinterpret_cast<const short8*>(&Kh[off]);
        short8 kl = *reinterpret_cast<const short8*>(&Klo[off]);
        a = __builtin_amdgcn_mfma_f32_16x16x32_bf16(qh[ks], kh, a, 0, 0, 0);
        a = __builtin_amdgcn_mfma_f32_16x16x32_bf16(ql[ks], kh, a, 0, 0, 0);
        a = __builtin_amdgcn_mfma_f32_16x16x32_bf16(qh[ks], kl, a, 0, 0, 0);
      }
      accS[ns] = a;
    }

    // decay + causal mask on C-layout (row=quad*4+r, col=ln), store fp32 Sc
    // in round-5's [row][t] layout (stride 65).
    int prow = quad * 4;
#pragma unroll
    for (int ns = 0; ns < 4; ++ns) {
      int t = t0 + ns * 16 + ln;
#pragma unroll
      for (int rr = 0; rr < 4; ++rr) {
        int s = s0 + w * 16 + prow + rr;
        int diff = s - t;
        float v = accS[ns][rr];
        Sc[(w * 16 + prow + rr) * 65 + (ns * 16 + ln)] =
            (diff >= 0) ? v * __expf((float)diff * logg) : 0.f;
      }
    }
    __syncthreads();

    // phase 2: VALU PV accumulate (round 5, proven verbatim)
    for (int tt = 0; tt < 64; ++tt) {
      float p = Sc[r2 * 65 + tt];
#pragma unroll
      for (int i = 0; i < 16; ++i)
        acc[i] += p * Vl[tt * 68 + sub * 16 + i];
    }
  }

  // GroupNorm epilogue (round 5, proven verbatim)
  float psum = 0.f, psq = 0.f;
#pragma unroll
  for (int i = 0; i < 16; ++i) { psum += acc[i]; psq += acc[i] * acc[i]; }
  __syncthreads();
  gnred[r2][sub] = psum;
  gnred[r2][4 + sub] = psq;
  __syncthreads();
  float sum = gnred[r2][0] + gnred[r2][1] + gnred[r2][2] + gnred[r2][3];
  float sq = gnred[r2][4] + gnred[r2][5] + gnred[r2][6] + gnred[r2][7];
  float mean = sum * (1.f / 64.f);
  float var = sq * (1.f / 64.f) - mean * mean;
  float rstd = rsqrtf(var + 1e-5f);

  size_t obase = ((size_t)(b * S_ + s0 + r2)) * HID_ + h * DH_ + sub * 16;
#pragma unroll
  for (int i = 0; i < 16; ++i) {
    float gw = gn_w[h * DH_ + sub * 16 + i];
    float gb = gn_b[h * DH_ + sub * 16 + i];
    retn[obase + i] = (acc[i] - mean) * rstd * gw + gb;
  }
}

// ---------------------------------------------------------------------------
// GEMM 1 (gate): unchanged, proven round 5.
// ---------------------------------------------------------------------------
__global__ __launch_bounds__(256) void gemm_gate_kernel(
    const unsigned short* __restrict__ A, const unsigned short* __restrict__ Bt,
    const float* __restrict__ retn, unsigned short* __restrict__ pre_hi,
    unsigned short* __restrict__ pre_lo) {
  const int K = HID_;
  __shared__ __align__(16) unsigned short Al[128 * 56];
  __shared__ __align__(16) unsigned short Bl[128 * 56];

  int tid = threadIdx.x;
  int lane = tid & 63, ln = lane & 15, quad = lane >> 4;
  int w = tid >> 6, wm = w >> 1, wn = w & 1;
  int m0 = blockIdx.y * 128, n0 = blockIdx.x * 128;

  floatx4 acc[4][4];
#pragma unroll
  for (int i = 0; i < 4; ++i)
#pragma unroll
    for (int j = 0; j < 4; ++j) acc[i][j] = (floatx4){0.f, 0.f, 0.f, 0.f};

  for (int k0 = 0; k0 < K; k0 += 32) {
    __syncthreads();
#pragma unroll
    for (int i = 0; i < 2; ++i) {
      int cid = tid + i * 256;
      int r = cid >> 2, c8 = (cid & 3) * 8;
      *reinterpret_cast<ushort8*>(&Al[r * 56 + c8]) =
          *reinterpret_cast<const ushort8*>(A + (size_t)(m0 + r) * K + k0 + c8);
      *reinterpret_cast<ushort8*>(&Bl[r * 56 + c8]) =
          *reinterpret_cast<const ushort8*>(Bt + (size_t)(n0 + r) * K + k0 + c8);
    }
    __syncthreads();

    short8 af[4], bfr[4];
#pragma unroll
    for (int i = 0; i < 4; ++i) {
      af[i] = *reinterpret_cast<const short8*>(&Al[(wm * 64 + i * 16 + ln) * 56 + quad * 8]);
      bfr[i] = *reinterpret_cast<const short8*>(&Bl[(wn * 64 + i * 16 + ln) * 56 + quad * 8]);
    }
#pragma unroll
    for (int mi = 0; mi < 4; ++mi)
#pragma unroll
      for (int ni = 0; ni < 4; ++ni)
        acc[mi][ni] = __builtin_amdgcn_mfma_f32_16x16x32_bf16(af[mi], bfr[ni], acc[mi][ni], 0, 0, 0);
  }

#pragma unroll
  for (int mi = 0; mi < 4; ++mi) {
#pragma unroll
    for (int r = 0; r < 4; ++r) {
      int row = m0 + wm * 64 + mi * 16 + quad * 4 + r;
#pragma unroll
      for (int ni = 0; ni < 4; ++ni) {
        int col = n0 + wn * 64 + ni * 16 + ln;
        float g = acc[mi][ni][r];
        float val = g * (1.f / (1.f + __expf(-g))) + retn[(size_t)row * HID_ + col];
        unsigned short hh = f2bf(val);
        size_t oidx = (size_t)row * HID_ + col;
        pre_hi[oidx] = hh;
        pre_lo[oidx] = f2bf(val - bf2f(hh));
      }
    }
  }
}

// ---------------------------------------------------------------------------
// GEMM 2 (output): unchanged, proven round 5.
// ---------------------------------------------------------------------------
__global__ __launch_bounds__(256) void gemm_out_kernel(
    const unsigned short* __restrict__ Ah, const unsigned short* __restrict__ Alo,
    const unsigned short* __restrict__ Bth, const unsigned short* __restrict__ Btlo,
    float* __restrict__ out_f) {
  const int K = HID_;
  __shared__ __align__(16) unsigned short AhS[128 * 56];
  __shared__ __align__(16) unsigned short AlS[128 * 56];
  __shared__ __align__(16) unsigned short BhS[128 * 56];
  __shared__ __align__(16) unsigned short BlS[128 * 56];

  int tid = threadIdx.x;
  int lane = tid & 63, ln = lane & 15, quad = lane >> 4;
  int w = tid >> 6, wm = w >> 1, wn = w & 1;
  int m0 = blockIdx.y * 128, n0 = blockIdx.x * 128;

  floatx4 acc[4][4];
#pragma unroll
  for (int i = 0; i < 4; ++i)
#pragma unroll
    for (int j = 0; j < 4; ++j) acc[i][j] = (floatx4){0.f, 0.f, 0.f, 0.f};

  for (int k0 = 0; k0 < K; k0 += 32) {
    __syncthreads();
#pragma unroll
    for (int i = 0; i < 2; ++i) {
      int cid = tid + i * 256;
      int r = cid >> 2, c8 = (cid & 3) * 8;
      size_t ga = (size_t)(m0 + r) * K + k0 + c8;
      size_t gb = (size_t)(n0 + r) * K + k0 + c8;
      *reinterpret_cast<ushort8*>(&AhS[r * 56 + c8]) = *reinterpret_cast<const ushort8*>(Ah + ga);
      *reinterpret_cast<ushort8*>(&AlS[r * 56 + c8]) = *reinterpret_cast<const ushort8*>(Alo + ga);
      *reinterpret_cast<ushort8*>(&BhS[r * 56 + c8]) = *reinterpret_cast<const ushort8*>(Bth + gb);
      *reinterpret_cast<ushort8*>(&BlS[r * 56 + c8]) = *reinterpret_cast<const ushort8*>(Btlo + gb);
    }
    __syncthreads();

    short8 afh[4], afl[4], bfh[4], bfl[4];
#pragma unroll
    for (int i = 0; i < 4; ++i) {
      int ao = (wm * 64 + i * 16 + ln) * 56 + quad * 8;
      int bo = (wn * 64 + i * 16 + ln) * 56 + quad * 8;
      afh[i] = *reinterpret_cast<const short8*>(&AhS[ao]);
      afl[i] = *reinterpret_cast<const short8*>(&AlS[ao]);
      bfh[i] = *reinterpret_cast<const short8*>(&BhS[bo]);
      bfl[i] = *reinterpret_cast<const short8*>(&BlS[bo]);
    }
#pragma unroll
    for (int mi = 0; mi < 4; ++mi)
#pragma unroll
      for (int ni = 0; ni < 4; ++ni) {
        floatx4 a = acc[mi][ni];
        a = __builtin_amdgcn_mfma_f32_16x16x32_bf16(afh[mi], bfh[ni], a, 0, 0, 0);
        a = __builtin_amdgcn_mfma_f32_16x16x32_bf16(afl[mi], bfh[ni], a, 0, 0, 0);
        a = __builtin_amdgcn_mfma_f32_16x16x32_bf16(afh[mi], bfl[ni], a, 0, 0, 0);
        acc[mi][ni] = a;
      }
  }

#pragma unroll
  for (int mi = 0; mi < 4; ++mi) {
#pragma unroll
    for (int r = 0; r < 4; ++r) {
      int row = m0 + wm * 64 + mi * 16 + quad * 4 + r;
#pragma unroll
      for (int ni = 0; ni < 4; ++ni) {
        int col = n0 + wn * 64 + ni * 16 + ln;
        out_f[(size_t)row * HID_ + col] = acc[mi][ni][r];
      }
    }
  }
}

// ---------------------------------------------------------------------------
extern "C" void kernel_launch(void* const* d_in, const int* in_sizes, int n_in,
                              void* d_out, int out_size, void* d_ws,
                              size_t ws_size, hipStream_t stream) {
  (void)in_sizes; (void)n_in; (void)out_size; (void)ws_size;
  const float* x = (const float*)d_in[0];
  const float* wq = (const float*)d_in[1];
  const float* bq = (const float*)d_in[2];
  const float* wk = (const float*)d_in[3];
  const float* bk = (const float*)d_in[4];
  const float* wv = (const float*)d_in[5];
  const float* theta = (const float*)d_in[6];
  const float* gn_w = (const float*)d_in[7];
  const float* gn_b = (const float*)d_in[8];
  const float* w1 = (const float*)d_in[9];
  const float* w2 = (const float*)d_in[10];

  const size_t MB = 1024 * 1024;
  char* ws = (char*)d_ws;
  unsigned short* x_bf   = (unsigned short*)(ws + 0 * MB);    //  8 MiB
  unsigned short* w1t    = (unsigned short*)(ws + 8 * MB);    //  2 MiB
  unsigned short* w2t_hi = (unsigned short*)(ws + 10 * MB);   //  2 MiB
  unsigned short* w2t_lo = (unsigned short*)(ws + 12 * MB);   //  2 MiB
  float*          q_f    = (float*)(ws + 14 * MB);            // 16 MiB (1 batch)
  float*          k_f    = (float*)(ws + 30 * MB);            // 16 MiB
  float*          v_f    = (float*)(ws + 46 * MB);            //  8 MiB
  float*          retn   = (float*)(ws + 54 * MB);            // 16 MiB (both batches)
  unsigned short* pre_hi = (unsigned short*)(ws + 14 * MB);   //  8 MiB (alias q_f)
  unsigned short* pre_lo = (unsigned short*)(ws + 22 * MB);   //  8 MiB
  float* out = (float*)d_out;

  convert_kernel<<<dim3(24576), 256, 0, stream>>>(x, w1, w2, x_bf, w1t, w2t_hi, w2t_lo);
  for (int b = 0; b < B_; ++b) {
    qkv_kernel<<<dim3(S_ / 64, H_), 256, 0, stream>>>(
        x, wq, bq, wk, bk, wv, theta, q_f, k_f, v_f, b);
    retention_hybrid_kernel<<<dim3(S_ / 64, H_), 256, 0, stream>>>(
        q_f, k_f, v_f, gn_w, gn_b, retn, b);
  }
  gemm_gate_kernel<<<dim3(HID_ / 128, (B_ * S_) / 128), 256, 0, stream>>>(
      x_bf, w1t, retn, pre_hi, pre_lo);
  gemm_out_kernel<<<dim3(HID_ / 128, (B_ * S_) / 128), 256, 0, stream>>>(
      pre_hi, pre_lo, w2t_hi, w2t_lo, out);
}